// Round 4
// baseline (216.399 us; speedup 1.0000x reference)
//
#include <hip/hip_runtime.h>
#include <hip/hip_cooperative_groups.h>
#include <math.h>

namespace cg = cooperative_groups;

// Problem constants
#define MM 4
#define BB 256
#define KK 64
#define HH 1024
#define NN 50
#define EE 1225
#define PP 64
#define CTOT 1375   // E + N*3
#define NPAD 1408   // cols padded to 11*128

typedef short short8 __attribute__((ext_vector_type(8)));
typedef float floatx4 __attribute__((ext_vector_type(4)));
typedef unsigned short ushort;

__device__ __forceinline__ ushort f2bf(float f) {
    union { float f; unsigned u; } v; v.f = f;
    unsigned r = v.u + 0x7fffu + ((v.u >> 16) & 1u);
    return (ushort)(r >> 16);
}

__device__ __forceinline__ float logsigm(float l) {
    // log sigmoid(-l) = -(max(l,0) + log1p(exp(-|l|)))
    return -(fmaxf(l, 0.0f) + log1pf(expf(-fabsf(l))));
}

__device__ __forceinline__ float wsum64(float v) {
    #pragma unroll
    for (int m = 1; m < 64; m <<= 1) v += __shfl_xor(v, m);
    return v;
}
__device__ __forceinline__ float wmax64(float v) {
    #pragma unroll
    for (int m = 1; m < 64; m <<= 1) v = fmaxf(v, __shfl_xor(v, m));
    return v;
}

struct SMg { short As[2][64][72]; short Bs[2][128][72]; };                 // 55296 B
struct SMf {
    int   ip[PP * NN];
    float Lb[EE];
    int   edges[1280];
    float lgfs[600];
    int   nE;
    float mred[4], wmaxs[4], klds;
};                                                                        // ~25.3 KB
union SMem {
    SMg    g;
    float  T[64 * 65];
    float4 z4[64];
    SMf    f;
};

// ---------------- mega cooperative kernel: 256 blocks x 256 threads ----------------
__global__ __launch_bounds__(256, 1) void mega(
        const float* __restrict__ mean, const float* __restrict__ logvar,
        const float* __restrict__ eps,  const float* __restrict__ W1,
        const float* __restrict__ b1,   const float* __restrict__ WA,
        const float* __restrict__ WF,   const float* __restrict__ bA,
        const float* __restrict__ bF,   const float* __restrict__ A,
        const float* __restrict__ Fx,   const float* __restrict__ coeff,
        const int*   __restrict__ perms,
        ushort* __restrict__ hB, ushort* __restrict__ Wt,
        float* __restrict__ Lbar, float* __restrict__ Sneg,
        float* __restrict__ lgF,  float* __restrict__ out) {
    __shared__ SMem sm;
    const int bid = blockIdx.x;
    const int t = threadIdx.x;

    // ================= Phase A: k1 (h=relu(Z@W1+b1)->bf16) + k0 (Wt transpose) =================
    {
        const int b = bid;
        if (t < 64) {
            float mv = mean[b * 64 + t];
            float lv = logvar[b * 64 + t];
            float sd = expf(0.5f * lv);
            float4 z;
            z.x = mv + sd * eps[(0 * BB + b) * 64 + t];
            z.y = mv + sd * eps[(1 * BB + b) * 64 + t];
            z.z = mv + sd * eps[(2 * BB + b) * 64 + t];
            z.w = mv + sd * eps[(3 * BB + b) * 64 + t];
            sm.z4[t] = z;
        }
        if (t < 4) Sneg[b * 4 + t] = 0.0f;
        __syncthreads();
        const int j0 = t * 4;
        float acc[4][4] = {};
        #pragma unroll 8
        for (int k = 0; k < 64; k++) {
            float4 w = *(const float4*)&W1[k * HH + j0];
            float4 z = sm.z4[k];
            acc[0][0] += z.x * w.x; acc[0][1] += z.x * w.y; acc[0][2] += z.x * w.z; acc[0][3] += z.x * w.w;
            acc[1][0] += z.y * w.x; acc[1][1] += z.y * w.y; acc[1][2] += z.y * w.z; acc[1][3] += z.y * w.w;
            acc[2][0] += z.z * w.x; acc[2][1] += z.z * w.y; acc[2][2] += z.z * w.z; acc[2][3] += z.z * w.w;
            acc[3][0] += z.w * w.x; acc[3][1] += z.w * w.y; acc[3][2] += z.w * w.z; acc[3][3] += z.w * w.w;
        }
        float4 bb = *(const float4*)&b1[j0];
        #pragma unroll
        for (int m = 0; m < 4; m++) {
            unsigned u0 = ((unsigned)f2bf(fmaxf(acc[m][0] + bb.x, 0.f))) |
                          ((unsigned)f2bf(fmaxf(acc[m][1] + bb.y, 0.f)) << 16);
            unsigned u1 = ((unsigned)f2bf(fmaxf(acc[m][2] + bb.z, 0.f))) |
                          ((unsigned)f2bf(fmaxf(acc[m][3] + bb.w, 0.f)) << 16);
            uint2 u; u.x = u0; u.y = u1;
            *(uint2*)&hB[(b * 4 + m) * HH + j0] = u;
        }
        __syncthreads();   // done with z4 before reusing union as T

        // k0 tiles: 352 tiles (16 kt x 22 nt) over 256 blocks
        for (int id = bid; id < 352; id += 256) {
            const int kt = id & 15, nt = id >> 4;
            const int k0 = kt * 64, n0 = nt * 64;
            #pragma unroll
            for (int i = 0; i < 16; i++) {
                int x = i * 256 + t;
                int kk = x >> 6, nn = x & 63;
                int gn = n0 + nn, gk = k0 + kk;
                float v = 0.f;
                if (gn < EE)        v = WA[gk * EE + gn];
                else if (gn < CTOT) v = WF[gk * 150 + (gn - EE)];
                sm.T[kk * 65 + nn] = v;
            }
            __syncthreads();
            #pragma unroll
            for (int i = 0; i < 16; i++) {
                int x = i * 256 + t;
                int nn = x >> 6, kk = x & 63;
                Wt[(n0 + nn) * 1024 + k0 + kk] = f2bf(sm.T[kk * 65 + nn]);
            }
            __syncthreads();
        }
    }

    cg::this_grid().sync();

    // ================= Phase B: MFMA GEMM + fused epilogue (176 tiles) =================
    if (bid < 176) {
        const int ct = bid % 11;     // 0..10
        const int rt = bid / 11;     // 0..15
        const int w = t >> 6, lane = t & 63;
        const int wm = w >> 1, wn = w & 1;
        const int quad = lane >> 4, l16 = lane & 15;
        floatx4 acc[2][4] = {};
        const int row0 = rt * 64, col0 = ct * 128;

        const int rA0 = t >> 3, koA = (t & 7) * 8;
        const int rA1 = rA0 + 32;
        const int rB0 = t >> 3;
        const ushort* pA0 = hB + (row0 + rA0) * 1024 + koA;
        const ushort* pA1 = hB + (row0 + rA1) * 1024 + koA;
        const ushort* pB  = Wt + (col0 + rB0) * 1024 + koA;

        short8 ra0, ra1, rb[4];
        ra0 = *(const short8*)(pA0);
        ra1 = *(const short8*)(pA1);
        #pragma unroll
        for (int i = 0; i < 4; i++) rb[i] = *(const short8*)(pB + i * 32 * 1024);
        // write buffer 0
        *(short8*)&sm.g.As[0][rA0][koA] = ra0;
        *(short8*)&sm.g.As[0][rA1][koA] = ra1;
        #pragma unroll
        for (int i = 0; i < 4; i++) *(short8*)&sm.g.Bs[0][i * 32 + rB0][koA] = rb[i];

        for (int ch = 0; ch < 16; ch++) {
            if (ch < 15) {
                const int off = (ch + 1) * 64;
                ra0 = *(const short8*)(pA0 + off);
                ra1 = *(const short8*)(pA1 + off);
                #pragma unroll
                for (int i = 0; i < 4; i++) rb[i] = *(const short8*)(pB + i * 32 * 1024 + off);
            }
            __syncthreads();   // buf[ch&1] fully written; all threads done with prev compute
            const int cur = ch & 1;
            #pragma unroll
            for (int kk = 0; kk < 2; kk++) {
                int ko = kk * 32 + quad * 8;
                short8 a0 = *(const short8*)&sm.g.As[cur][wm * 32 + l16][ko];
                short8 a1 = *(const short8*)&sm.g.As[cur][wm * 32 + 16 + l16][ko];
                short8 b0 = *(const short8*)&sm.g.Bs[cur][wn * 64 + l16][ko];
                short8 b1 = *(const short8*)&sm.g.Bs[cur][wn * 64 + 16 + l16][ko];
                short8 b2 = *(const short8*)&sm.g.Bs[cur][wn * 64 + 32 + l16][ko];
                short8 b3 = *(const short8*)&sm.g.Bs[cur][wn * 64 + 48 + l16][ko];
                acc[0][0] = __builtin_amdgcn_mfma_f32_16x16x32_bf16(a0, b0, acc[0][0], 0, 0, 0);
                acc[0][1] = __builtin_amdgcn_mfma_f32_16x16x32_bf16(a0, b1, acc[0][1], 0, 0, 0);
                acc[0][2] = __builtin_amdgcn_mfma_f32_16x16x32_bf16(a0, b2, acc[0][2], 0, 0, 0);
                acc[0][3] = __builtin_amdgcn_mfma_f32_16x16x32_bf16(a0, b3, acc[0][3], 0, 0, 0);
                acc[1][0] = __builtin_amdgcn_mfma_f32_16x16x32_bf16(a1, b0, acc[1][0], 0, 0, 0);
                acc[1][1] = __builtin_amdgcn_mfma_f32_16x16x32_bf16(a1, b1, acc[1][1], 0, 0, 0);
                acc[1][2] = __builtin_amdgcn_mfma_f32_16x16x32_bf16(a1, b2, acc[1][2], 0, 0, 0);
                acc[1][3] = __builtin_amdgcn_mfma_f32_16x16x32_bf16(a1, b3, acc[1][3], 0, 0, 0);
            }
            if (ch < 15) {
                const int nxt = cur ^ 1;
                *(short8*)&sm.g.As[nxt][rA0][koA] = ra0;
                *(short8*)&sm.g.As[nxt][rA1][koA] = ra1;
                #pragma unroll
                for (int i = 0; i < 4; i++) *(short8*)&sm.g.Bs[nxt][i * 32 + rB0][koA] = rb[i];
            }
        }

        // Epilogue: C/D layout col=lane&15, row=quad*4+reg -> lane's 4 regs = graph b, m=0..3
        #pragma unroll
        for (int mi = 0; mi < 2; mi++) {
            const int grow = row0 + wm * 32 + mi * 16 + quad * 4;
            const int b = grow >> 2;
            float sn0 = 0.f, sn1 = 0.f, sn2 = 0.f, sn3 = 0.f;
            #pragma unroll
            for (int ni = 0; ni < 4; ni++) {
                int gc = col0 + wn * 64 + ni * 16 + l16;
                floatx4 a = acc[mi][ni];
                if (gc < EE) {
                    float bias = bA[gc];
                    float l0 = a[0] + bias, l1 = a[1] + bias, l2 = a[2] + bias, l3 = a[3] + bias;
                    Lbar[b * EE + gc] = 0.25f * (l0 + l1 + l2 + l3);
                    sn0 += logsigm(l0); sn1 += logsigm(l1); sn2 += logsigm(l2); sn3 += logsigm(l3);
                } else if (gc < CTOT) {
                    int c2 = gc - EE;
                    float bias = bF[c2];
                    lgF[(b * 4 + 0) * 150 + c2] = a[0] + bias;
                    lgF[(b * 4 + 1) * 150 + c2] = a[1] + bias;
                    lgF[(b * 4 + 2) * 150 + c2] = a[2] + bias;
                    lgF[(b * 4 + 3) * 150 + c2] = a[3] + bias;
                }
            }
            #pragma unroll
            for (int msk = 1; msk < 16; msk <<= 1) {
                sn0 += __shfl_xor(sn0, msk);
                sn1 += __shfl_xor(sn1, msk);
                sn2 += __shfl_xor(sn2, msk);
                sn3 += __shfl_xor(sn3, msk);
            }
            if (l16 == 0) {
                atomicAdd(&Sneg[b * 4 + 0], sn0);
                atomicAdd(&Sneg[b * 4 + 1], sn1);
                atomicAdd(&Sneg[b * 4 + 2], sn2);
                atomicAdd(&Sneg[b * 4 + 3], sn3);
            }
        }
    }

    cg::this_grid().sync();

    // ================= Phase C: per-graph finalization =================
    {
        const int b = bid;
        const int w = t >> 6, lane = t & 63;
        if (t == 0) sm.f.nE = 0;
        for (int x = t; x < PP * NN; x += 256) {
            int p = x / NN, i = x - p * NN;
            sm.f.ip[p * NN + perms[x]] = i;
        }
        for (int x = t; x < EE; x += 256) sm.f.Lb[x] = Lbar[b * EE + x];
        for (int x = t; x < 600; x += 256) sm.f.lgfs[x] = lgF[b * 600 + x];
        __syncthreads();

        // coalesced linear scan of A[b] (lower triangle test)
        for (int x = t; x < 2500; x += 256) {
            int i = x / NN, j = x - i * NN;
            if (j < i) {
                float a = A[b * 2500 + x];
                if (a != 0.0f) { int id = atomicAdd(&sm.f.nE, 1); sm.f.edges[id] = (i << 8) | j; }
            }
        }

        {
            float l0 = 0.f, l1 = 0.f, l2 = -INFINITY, x0 = 0.f, x1 = 0.f, x2 = 0.f;
            bool v = lane < NN;
            if (v) {
                l0 = sm.f.lgfs[w * 150 + lane * 3 + 0];
                l1 = sm.f.lgfs[w * 150 + lane * 3 + 1];
                l2 = sm.f.lgfs[w * 150 + lane * 3 + 2];
                x0 = Fx[b * 150 + lane * 3 + 0];
                x1 = Fx[b * 150 + lane * 3 + 1];
                x2 = Fx[b * 150 + lane * 3 + 2];
            }
            float mx = wmax64(l2);
            float es = v ? expf(l2 - mx) : 0.f;
            es = wsum64(es);
            float lse = mx + logf(es);
            float val = 0.f;
            if (v) {
                val = coeff[0] * (logsigm(l0) + x0 * l0)
                    + coeff[1] * (logsigm(l1) + x1 * l1)
                    + coeff[2] * (x2 * (l2 - lse));
            }
            val = wsum64(val);
            if (lane == 0) sm.f.mred[w] = val;
        }
        if (w == 0) {
            float lv = logvar[b * 64 + lane];
            float mn = mean[b * 64 + lane];
            float term = 0.5f * (expf(lv) + mn * mn - 1.0f - lv);
            term = wsum64(term);
            if (lane == 0) sm.f.klds = term;
        }
        __syncthreads();

        const int ne = sm.f.nE;
        float lmax = -INFINITY;
        for (int p = w; p < PP; p += 4) {
            const int* ipp = &sm.f.ip[p * NN];
            float acc = 0.f;
            for (int x = lane; x < ne; x += 64) {
                int ed = sm.f.edges[x];
                int iu = ipp[ed >> 8], iv = ipp[ed & 255];
                int ii = max(iu, iv), jj = min(iu, iv);
                acc += sm.f.Lb[ii * (ii - 1) / 2 + jj];
            }
            acc = wsum64(acc);
            lmax = fmaxf(lmax, acc);
        }
        if (lane == 0) sm.f.wmaxs[w] = lmax;
        __syncthreads();
        if (t == 0) {
            float dmax = fmaxf(fmaxf(sm.f.wmaxs[0], sm.f.wmaxs[1]), fmaxf(sm.f.wmaxs[2], sm.f.wmaxs[3]));
            float sbar = 0.25f * (Sneg[b * 4 + 0] + Sneg[b * 4 + 1] + Sneg[b * 4 + 2] + Sneg[b * 4 + 3]);
            float fxv  = 0.25f * (sm.f.mred[0] + sm.f.mred[1] + sm.f.mred[2] + sm.f.mred[3]);
            out[b] = (sbar + dmax) + fxv - sm.f.klds;
        }
    }
}

// ================= Fallback path (round-3 kernels) =================
__global__ __launch_bounds__(256) void kA(const float* __restrict__ mean,
                                          const float* __restrict__ logvar,
                                          const float* __restrict__ eps,
                                          const float* __restrict__ W1,
                                          const float* __restrict__ b1,
                                          const float* __restrict__ WA,
                                          const float* __restrict__ WF,
                                          ushort* __restrict__ hB,
                                          ushort* __restrict__ Wt,
                                          float* __restrict__ Sneg) {
    const int t = threadIdx.x;
    __shared__ float smem[64 * 65];
    if (blockIdx.x < 256) {
        const int b = blockIdx.x;
        float4* z4 = (float4*)smem;
        if (t < 64) {
            float mv = mean[b * 64 + t];
            float lv = logvar[b * 64 + t];
            float sd = expf(0.5f * lv);
            float4 z;
            z.x = mv + sd * eps[(0 * BB + b) * 64 + t];
            z.y = mv + sd * eps[(1 * BB + b) * 64 + t];
            z.z = mv + sd * eps[(2 * BB + b) * 64 + t];
            z.w = mv + sd * eps[(3 * BB + b) * 64 + t];
            z4[t] = z;
        }
        if (t < 4) Sneg[b * 4 + t] = 0.0f;
        __syncthreads();
        const int j0 = t * 4;
        float acc[4][4] = {};
        #pragma unroll 8
        for (int k = 0; k < 64; k++) {
            float4 w = *(const float4*)&W1[k * HH + j0];
            float4 z = z4[k];
            acc[0][0] += z.x * w.x; acc[0][1] += z.x * w.y; acc[0][2] += z.x * w.z; acc[0][3] += z.x * w.w;
            acc[1][0] += z.y * w.x; acc[1][1] += z.y * w.y; acc[1][2] += z.y * w.z; acc[1][3] += z.y * w.w;
            acc[2][0] += z.z * w.x; acc[2][1] += z.z * w.y; acc[2][2] += z.z * w.z; acc[2][3] += z.z * w.w;
            acc[3][0] += z.w * w.x; acc[3][1] += z.w * w.y; acc[3][2] += z.w * w.z; acc[3][3] += z.w * w.w;
        }
        float4 bb = *(const float4*)&b1[j0];
        #pragma unroll
        for (int m = 0; m < 4; m++) {
            unsigned u0 = ((unsigned)f2bf(fmaxf(acc[m][0] + bb.x, 0.f))) |
                          ((unsigned)f2bf(fmaxf(acc[m][1] + bb.y, 0.f)) << 16);
            unsigned u1 = ((unsigned)f2bf(fmaxf(acc[m][2] + bb.z, 0.f))) |
                          ((unsigned)f2bf(fmaxf(acc[m][3] + bb.w, 0.f)) << 16);
            uint2 u; u.x = u0; u.y = u1;
            *(uint2*)&hB[(b * 4 + m) * HH + j0] = u;
        }
    } else {
        const int id = blockIdx.x - 256;
        const int kt = id & 15, nt = id >> 4;
        float* T = smem;
        const int k0 = kt * 64, n0 = nt * 64;
        #pragma unroll
        for (int i = 0; i < 16; i++) {
            int x = i * 256 + t;
            int kk = x >> 6, nn = x & 63;
            int gn = n0 + nn, gk = k0 + kk;
            float v = 0.f;
            if (gn < EE)        v = WA[gk * EE + gn];
            else if (gn < CTOT) v = WF[gk * 150 + (gn - EE)];
            T[kk * 65 + nn] = v;
        }
        __syncthreads();
        #pragma unroll
        for (int i = 0; i < 16; i++) {
            int x = i * 256 + t;
            int nn = x >> 6, kk = x & 63;
            Wt[(n0 + nn) * 1024 + k0 + kk] = f2bf(T[kk * 65 + nn]);
        }
    }
}

__global__ __launch_bounds__(256) void k2(const ushort* __restrict__ hB,
                                          const ushort* __restrict__ Wt,
                                          const float* __restrict__ bA,
                                          const float* __restrict__ bF,
                                          float* __restrict__ Lbar,
                                          float* __restrict__ Sneg,
                                          float* __restrict__ lgF) {
    const int ct = blockIdx.x;
    const int rt = blockIdx.y;
    const int t = threadIdx.x;
    const int w = t >> 6, lane = t & 63;
    const int wm = w >> 1, wn = w & 1;
    const int quad = lane >> 4, l16 = lane & 15;
    __shared__ short As[64][72];
    __shared__ short Bs[128][72];
    floatx4 acc[2][4] = {};
    const int row0 = rt * 64, col0 = ct * 128;
    const int rA0 = t >> 3, koA = (t & 7) * 8;
    const int rA1 = (256 + t) >> 3;
    const int rB0 = t >> 3;
    const ushort* pA0 = hB + (row0 + rA0) * 1024 + koA;
    const ushort* pA1 = hB + (row0 + rA1) * 1024 + koA;
    const ushort* pB  = Wt + (col0 + rB0) * 1024 + koA;
    short8 ra[2], rb[4];
    ra[0] = *(const short8*)(pA0);
    ra[1] = *(const short8*)(pA1);
    #pragma unroll
    for (int i = 0; i < 4; i++) rb[i] = *(const short8*)(pB + i * 32 * 1024);
    for (int ch = 0; ch < 16; ch++) {
        __syncthreads();
        *(short8*)&As[rA0][koA] = ra[0];
        *(short8*)&As[rA1][koA] = ra[1];
        #pragma unroll
        for (int i = 0; i < 4; i++) *(short8*)&Bs[i * 32 + rB0][koA] = rb[i];
        __syncthreads();
        if (ch < 15) {
            const int off = (ch + 1) * 64;
            ra[0] = *(const short8*)(pA0 + off);
            ra[1] = *(const short8*)(pA1 + off);
            #pragma unroll
            for (int i = 0; i < 4; i++) rb[i] = *(const short8*)(pB + i * 32 * 1024 + off);
        }
        #pragma unroll
        for (int kk = 0; kk < 2; kk++) {
            int ko = kk * 32 + quad * 8;
            short8 a0 = *(const short8*)&As[wm * 32 + l16][ko];
            short8 a1 = *(const short8*)&As[wm * 32 + 16 + l16][ko];
            short8 b0 = *(const short8*)&Bs[wn * 64 + l16][ko];
            short8 b1 = *(const short8*)&Bs[wn * 64 + 16 + l16][ko];
            short8 b2 = *(const short8*)&Bs[wn * 64 + 32 + l16][ko];
            short8 b3 = *(const short8*)&Bs[wn * 64 + 48 + l16][ko];
            acc[0][0] = __builtin_amdgcn_mfma_f32_16x16x32_bf16(a0, b0, acc[0][0], 0, 0, 0);
            acc[0][1] = __builtin_amdgcn_mfma_f32_16x16x32_bf16(a0, b1, acc[0][1], 0, 0, 0);
            acc[0][2] = __builtin_amdgcn_mfma_f32_16x16x32_bf16(a0, b2, acc[0][2], 0, 0, 0);
            acc[0][3] = __builtin_amdgcn_mfma_f32_16x16x32_bf16(a0, b3, acc[0][3], 0, 0, 0);
            acc[1][0] = __builtin_amdgcn_mfma_f32_16x16x32_bf16(a1, b0, acc[1][0], 0, 0, 0);
            acc[1][1] = __builtin_amdgcn_mfma_f32_16x16x32_bf16(a1, b1, acc[1][1], 0, 0, 0);
            acc[1][2] = __builtin_amdgcn_mfma_f32_16x16x32_bf16(a1, b2, acc[1][2], 0, 0, 0);
            acc[1][3] = __builtin_amdgcn_mfma_f32_16x16x32_bf16(a1, b3, acc[1][3], 0, 0, 0);
        }
    }
    #pragma unroll
    for (int mi = 0; mi < 2; mi++) {
        const int grow = row0 + wm * 32 + mi * 16 + quad * 4;
        const int b = grow >> 2;
        float sn0 = 0.f, sn1 = 0.f, sn2 = 0.f, sn3 = 0.f;
        #pragma unroll
        for (int ni = 0; ni < 4; ni++) {
            int gc = col0 + wn * 64 + ni * 16 + l16;
            floatx4 a = acc[mi][ni];
            if (gc < EE) {
                float bias = bA[gc];
                float l0 = a[0] + bias, l1 = a[1] + bias, l2 = a[2] + bias, l3 = a[3] + bias;
                Lbar[b * EE + gc] = 0.25f * (l0 + l1 + l2 + l3);
                sn0 += logsigm(l0); sn1 += logsigm(l1); sn2 += logsigm(l2); sn3 += logsigm(l3);
            } else if (gc < CTOT) {
                int c2 = gc - EE;
                float bias = bF[c2];
                lgF[(b * 4 + 0) * 150 + c2] = a[0] + bias;
                lgF[(b * 4 + 1) * 150 + c2] = a[1] + bias;
                lgF[(b * 4 + 2) * 150 + c2] = a[2] + bias;
                lgF[(b * 4 + 3) * 150 + c2] = a[3] + bias;
            }
        }
        #pragma unroll
        for (int msk = 1; msk < 16; msk <<= 1) {
            sn0 += __shfl_xor(sn0, msk);
            sn1 += __shfl_xor(sn1, msk);
            sn2 += __shfl_xor(sn2, msk);
            sn3 += __shfl_xor(sn3, msk);
        }
        if (l16 == 0) {
            atomicAdd(&Sneg[b * 4 + 0], sn0);
            atomicAdd(&Sneg[b * 4 + 1], sn1);
            atomicAdd(&Sneg[b * 4 + 2], sn2);
            atomicAdd(&Sneg[b * 4 + 3], sn3);
        }
    }
}

__global__ __launch_bounds__(256) void k4(const float* __restrict__ mean,
                                          const float* __restrict__ logvar,
                                          const float* __restrict__ A,
                                          const float* __restrict__ Fx,
                                          const float* __restrict__ coeff,
                                          const int* __restrict__ perms,
                                          const float* __restrict__ Lbar,
                                          const float* __restrict__ Sneg,
                                          const float* __restrict__ lgF,
                                          float* __restrict__ out) {
    const int b = blockIdx.x;
    const int t = threadIdx.x;
    const int w = t >> 6, lane = t & 63;
    __shared__ SMf f;
    if (t == 0) f.nE = 0;
    for (int x = t; x < PP * NN; x += 256) {
        int p = x / NN, i = x - p * NN;
        f.ip[p * NN + perms[x]] = i;
    }
    for (int x = t; x < EE; x += 256) f.Lb[x] = Lbar[b * EE + x];
    for (int x = t; x < 600; x += 256) f.lgfs[x] = lgF[b * 600 + x];
    __syncthreads();
    for (int x = t; x < 2500; x += 256) {
        int i = x / NN, j = x - i * NN;
        if (j < i) {
            float a = A[b * 2500 + x];
            if (a != 0.0f) { int id = atomicAdd(&f.nE, 1); f.edges[id] = (i << 8) | j; }
        }
    }
    {
        float l0 = 0.f, l1 = 0.f, l2 = -INFINITY, x0 = 0.f, x1 = 0.f, x2 = 0.f;
        bool v = lane < NN;
        if (v) {
            l0 = f.lgfs[w * 150 + lane * 3 + 0];
            l1 = f.lgfs[w * 150 + lane * 3 + 1];
            l2 = f.lgfs[w * 150 + lane * 3 + 2];
            x0 = Fx[b * 150 + lane * 3 + 0];
            x1 = Fx[b * 150 + lane * 3 + 1];
            x2 = Fx[b * 150 + lane * 3 + 2];
        }
        float mx = wmax64(l2);
        float es = v ? expf(l2 - mx) : 0.f;
        es = wsum64(es);
        float lse = mx + logf(es);
        float val = 0.f;
        if (v) {
            val = coeff[0] * (logsigm(l0) + x0 * l0)
                + coeff[1] * (logsigm(l1) + x1 * l1)
                + coeff[2] * (x2 * (l2 - lse));
        }
        val = wsum64(val);
        if (lane == 0) f.mred[w] = val;
    }
    if (w == 0) {
        float lv = logvar[b * 64 + lane];
        float mn = mean[b * 64 + lane];
        float term = 0.5f * (expf(lv) + mn * mn - 1.0f - lv);
        term = wsum64(term);
        if (lane == 0) f.klds = term;
    }
    __syncthreads();
    const int ne = f.nE;
    float lmax = -INFINITY;
    for (int p = w; p < PP; p += 4) {
        const int* ipp = &f.ip[p * NN];
        float acc = 0.f;
        for (int x = lane; x < ne; x += 64) {
            int ed = f.edges[x];
            int iu = ipp[ed >> 8], iv = ipp[ed & 255];
            int ii = max(iu, iv), jj = min(iu, iv);
            acc += f.Lb[ii * (ii - 1) / 2 + jj];
        }
        acc = wsum64(acc);
        lmax = fmaxf(lmax, acc);
    }
    if (lane == 0) f.wmaxs[w] = lmax;
    __syncthreads();
    if (t == 0) {
        float dmax = fmaxf(fmaxf(f.wmaxs[0], f.wmaxs[1]), fmaxf(f.wmaxs[2], f.wmaxs[3]));
        float sbar = 0.25f * (Sneg[b * 4 + 0] + Sneg[b * 4 + 1] + Sneg[b * 4 + 2] + Sneg[b * 4 + 3]);
        float fxv  = 0.25f * (f.mred[0] + f.mred[1] + f.mred[2] + f.mred[3]);
        out[b] = (sbar + dmax) + fxv - f.klds;
    }
}

extern "C" void kernel_launch(void* const* d_in, const int* in_sizes, int n_in,
                              void* d_out, int out_size, void* d_ws, size_t ws_size,
                              hipStream_t stream) {
    const float* mean   = (const float*)d_in[0];
    const float* logvar = (const float*)d_in[1];
    const float* eps    = (const float*)d_in[2];
    const float* W1     = (const float*)d_in[3];
    const float* b1     = (const float*)d_in[4];
    const float* WA     = (const float*)d_in[5];
    const float* bA     = (const float*)d_in[6];
    const float* WF     = (const float*)d_in[7];
    const float* bF     = (const float*)d_in[8];
    const float* A      = (const float*)d_in[9];
    const float* Fx     = (const float*)d_in[10];
    const float* coeff  = (const float*)d_in[11];
    const int*   perms  = (const int*)d_in[12];
    float* out = (float*)d_out;

    ushort* Wt   = (ushort*)d_ws;               // 1408*1024 bf16
    ushort* hB   = Wt + NPAD * 1024;            // 1024*1024 bf16
    float*  Lbar = (float*)(hB + 1024 * 1024);  // 256*1225
    float*  Sneg = Lbar + BB * EE;              // 1024 (zeroed in phase A)
    float*  lgF  = Sneg + 1024;                 // 1024*150

    void* args[] = { (void*)&mean, (void*)&logvar, (void*)&eps, (void*)&W1, (void*)&b1,
                     (void*)&WA, (void*)&WF, (void*)&bA, (void*)&bF, (void*)&A,
                     (void*)&Fx, (void*)&coeff, (void*)&perms,
                     (void*)&hB, (void*)&Wt, (void*)&Lbar, (void*)&Sneg, (void*)&lgF, (void*)&out };
    hipError_t e = hipLaunchCooperativeKernel((void*)mega, dim3(256), dim3(256), args, 0, stream);
    if (e != hipSuccess) {
        // fallback: 3-launch path (same computation)
        kA<<<dim3(608), dim3(256), 0, stream>>>(mean, logvar, eps, W1, b1, WA, WF, hB, Wt, Sneg);
        k2<<<dim3(11, 16), dim3(256), 0, stream>>>(hB, Wt, bA, bF, Lbar, Sneg, lgF);
        k4<<<dim3(BB), dim3(256), 0, stream>>>(mean, logvar, A, Fx, coeff, perms, Lbar, Sneg, lgF, out);
    }
}

// Round 5
// 136.262 us; speedup vs baseline: 1.5881x; 1.5881x over previous
//
#include <hip/hip_runtime.h>
#include <math.h>

// Problem constants
#define MM 4
#define BB 256
#define KK 64
#define HH 1024
#define NN 50
#define EE 1225
#define PP 64
#define CTOT 1375   // E + N*3
#define NPAD 1408   // cols padded to 11*128

typedef short short8 __attribute__((ext_vector_type(8)));
typedef float floatx4 __attribute__((ext_vector_type(4)));
typedef unsigned short ushort;

__device__ __forceinline__ ushort f2bf(float f) {
    union { float f; unsigned u; } v; v.f = f;
    unsigned r = v.u + 0x7fffu + ((v.u >> 16) & 1u);
    return (ushort)(r >> 16);
}

__device__ __forceinline__ float logsigm(float l) {
    // log sigmoid(-l) = -(max(l,0) + log1p(exp(-|l|)))
    return -(fmaxf(l, 0.0f) + log1pf(expf(-fabsf(l))));
}

__device__ __forceinline__ float wsum64(float v) {
    #pragma unroll
    for (int m = 1; m < 64; m <<= 1) v += __shfl_xor(v, m);
    return v;
}
__device__ __forceinline__ float wmax64(float v) {
    #pragma unroll
    for (int m = 1; m < 64; m <<= 1) v = fmaxf(v, __shfl_xor(v, m));
    return v;
}

// kA: fused weight transpose (blocks 256..607) + per-graph work (blocks 0..255):
//   h = relu(Z@W1+b1) -> bf16, edge extraction from A, KLD, Sneg zero-init.
__global__ __launch_bounds__(256) void kA(const float* __restrict__ mean,
                                          const float* __restrict__ logvar,
                                          const float* __restrict__ eps,
                                          const float* __restrict__ W1,
                                          const float* __restrict__ b1,
                                          const float* __restrict__ WA,
                                          const float* __restrict__ WF,
                                          const float* __restrict__ A,
                                          ushort* __restrict__ hB,
                                          ushort* __restrict__ Wt,
                                          float* __restrict__ Sneg,
                                          int*   __restrict__ edgesG,
                                          int*   __restrict__ cntG,
                                          float* __restrict__ kldG) {
    const int t = threadIdx.x;
    __shared__ float smem[64 * 65];
    __shared__ int cnt;

    if (blockIdx.x < 256) {
        // ---- per-graph block ----
        const int b = blockIdx.x;
        float4* z4 = (float4*)smem;
        if (t == 0) cnt = 0;
        if (t < 64) {
            float mv = mean[b * 64 + t];
            float lv = logvar[b * 64 + t];
            float sd = expf(0.5f * lv);
            float4 z;
            z.x = mv + sd * eps[(0 * BB + b) * 64 + t];
            z.y = mv + sd * eps[(1 * BB + b) * 64 + t];
            z.z = mv + sd * eps[(2 * BB + b) * 64 + t];
            z.w = mv + sd * eps[(3 * BB + b) * 64 + t];
            z4[t] = z;
            // KLD (wave 0, one lane per latent dim)
            float term = 0.5f * (expf(lv) + mv * mv - 1.0f - lv);
            term = wsum64(term);
            if (t == 0) kldG[b] = term;
        }
        if (t < 4) Sneg[b * 4 + t] = 0.0f;
        __syncthreads();
        const int j0 = t * 4;
        float acc[4][4] = {};   // [m][jc]
        #pragma unroll 8
        for (int k = 0; k < 64; k++) {
            float4 w = *(const float4*)&W1[k * HH + j0];
            float4 z = z4[k];
            acc[0][0] += z.x * w.x; acc[0][1] += z.x * w.y; acc[0][2] += z.x * w.z; acc[0][3] += z.x * w.w;
            acc[1][0] += z.y * w.x; acc[1][1] += z.y * w.y; acc[1][2] += z.y * w.z; acc[1][3] += z.y * w.w;
            acc[2][0] += z.z * w.x; acc[2][1] += z.z * w.y; acc[2][2] += z.z * w.z; acc[2][3] += z.z * w.w;
            acc[3][0] += z.w * w.x; acc[3][1] += z.w * w.y; acc[3][2] += z.w * w.z; acc[3][3] += z.w * w.w;
        }
        float4 bb = *(const float4*)&b1[j0];
        #pragma unroll
        for (int m = 0; m < 4; m++) {
            unsigned u0 = ((unsigned)f2bf(fmaxf(acc[m][0] + bb.x, 0.f))) |
                          ((unsigned)f2bf(fmaxf(acc[m][1] + bb.y, 0.f)) << 16);
            unsigned u1 = ((unsigned)f2bf(fmaxf(acc[m][2] + bb.z, 0.f))) |
                          ((unsigned)f2bf(fmaxf(acc[m][3] + bb.w, 0.f)) << 16);
            uint2 u; u.x = u0; u.y = u1;
            *(uint2*)&hB[(b * 4 + m) * HH + j0] = u;
        }
        // ---- edge extraction: coalesced scan of A[b], lower triangle ----
        for (int x = t; x < 2500; x += 256) {
            int i = x / NN, j = x - i * NN;
            if (j < i) {
                float a = A[b * 2500 + x];
                if (a != 0.0f) { int id = atomicAdd(&cnt, 1); edgesG[b * 256 + id] = (i << 8) | j; }
            }
        }
        __syncthreads();
        if (t == 0) cntG[b] = cnt;
    } else {
        // ---- Wt[n][k] = transpose of [WA | WF] (bf16, zero-padded cols) ----
        const int id = blockIdx.x - 256;
        const int kt = id & 15, nt = id >> 4;
        float* T = smem;   // [64][65]
        const int k0 = kt * 64, n0 = nt * 64;
        #pragma unroll
        for (int i = 0; i < 16; i++) {
            int x = i * 256 + t;
            int kk = x >> 6, nn = x & 63;
            int gn = n0 + nn, gk = k0 + kk;
            float v = 0.f;
            if (gn < EE)        v = WA[gk * EE + gn];
            else if (gn < CTOT) v = WF[gk * 150 + (gn - EE)];
            T[kk * 65 + nn] = v;
        }
        __syncthreads();
        #pragma unroll
        for (int i = 0; i < 16; i++) {
            int x = i * 256 + t;
            int nn = x >> 6, kk = x & 63;
            Wt[(n0 + nn) * 1024 + k0 + kk] = f2bf(T[kk * 65 + nn]);
        }
    }
}

// K2: MFMA GEMM logits[1024][1375] = hB @ Wt^T with fused epilogue + register
// double-buffer prefetch. Block tile 64x128, 4 waves (2x2), wave 32x64 = 2x4 MFMA 16x16x32.
__global__ __launch_bounds__(256) void k2(const ushort* __restrict__ hB,
                                          const ushort* __restrict__ Wt,
                                          const float* __restrict__ bA,
                                          const float* __restrict__ bF,
                                          float* __restrict__ Lbar,
                                          float* __restrict__ Sneg,
                                          float* __restrict__ lgF) {
    const int ct = blockIdx.x;   // 0..10
    const int rt = blockIdx.y;   // 0..15
    const int t = threadIdx.x;
    const int w = t >> 6, lane = t & 63;
    const int wm = w >> 1, wn = w & 1;
    const int quad = lane >> 4, l16 = lane & 15;
    __shared__ short As[64][72];
    __shared__ short Bs[128][72];
    floatx4 acc[2][4] = {};
    const int row0 = rt * 64, col0 = ct * 128;

    const int rA0 = t >> 3, koA = (t & 7) * 8;
    const int rA1 = (256 + t) >> 3;
    const int rB0 = t >> 3;
    const ushort* pA0 = hB + (row0 + rA0) * 1024 + koA;
    const ushort* pA1 = hB + (row0 + rA1) * 1024 + koA;
    const ushort* pB  = Wt + (col0 + rB0) * 1024 + koA;

    short8 ra[2], rb[4];
    ra[0] = *(const short8*)(pA0);
    ra[1] = *(const short8*)(pA1);
    #pragma unroll
    for (int i = 0; i < 4; i++) rb[i] = *(const short8*)(pB + i * 32 * 1024);

    for (int ch = 0; ch < 16; ch++) {
        __syncthreads();
        *(short8*)&As[rA0][koA] = ra[0];
        *(short8*)&As[rA1][koA] = ra[1];
        #pragma unroll
        for (int i = 0; i < 4; i++) *(short8*)&Bs[i * 32 + rB0][koA] = rb[i];
        __syncthreads();
        if (ch < 15) {
            const int off = (ch + 1) * 64;
            ra[0] = *(const short8*)(pA0 + off);
            ra[1] = *(const short8*)(pA1 + off);
            #pragma unroll
            for (int i = 0; i < 4; i++) rb[i] = *(const short8*)(pB + i * 32 * 1024 + off);
        }
        #pragma unroll
        for (int kk = 0; kk < 2; kk++) {
            int ko = kk * 32 + quad * 8;
            short8 a0 = *(const short8*)&As[wm * 32 + l16][ko];
            short8 a1 = *(const short8*)&As[wm * 32 + 16 + l16][ko];
            short8 b0 = *(const short8*)&Bs[wn * 64 + l16][ko];
            short8 b1 = *(const short8*)&Bs[wn * 64 + 16 + l16][ko];
            short8 b2 = *(const short8*)&Bs[wn * 64 + 32 + l16][ko];
            short8 b3 = *(const short8*)&Bs[wn * 64 + 48 + l16][ko];
            acc[0][0] = __builtin_amdgcn_mfma_f32_16x16x32_bf16(a0, b0, acc[0][0], 0, 0, 0);
            acc[0][1] = __builtin_amdgcn_mfma_f32_16x16x32_bf16(a0, b1, acc[0][1], 0, 0, 0);
            acc[0][2] = __builtin_amdgcn_mfma_f32_16x16x32_bf16(a0, b2, acc[0][2], 0, 0, 0);
            acc[0][3] = __builtin_amdgcn_mfma_f32_16x16x32_bf16(a0, b3, acc[0][3], 0, 0, 0);
            acc[1][0] = __builtin_amdgcn_mfma_f32_16x16x32_bf16(a1, b0, acc[1][0], 0, 0, 0);
            acc[1][1] = __builtin_amdgcn_mfma_f32_16x16x32_bf16(a1, b1, acc[1][1], 0, 0, 0);
            acc[1][2] = __builtin_amdgcn_mfma_f32_16x16x32_bf16(a1, b2, acc[1][2], 0, 0, 0);
            acc[1][3] = __builtin_amdgcn_mfma_f32_16x16x32_bf16(a1, b3, acc[1][3], 0, 0, 0);
        }
    }

    // Epilogue: C/D layout col=lane&15, row=quad*4+reg -> lane's 4 regs = graph b, m=0..3
    #pragma unroll
    for (int mi = 0; mi < 2; mi++) {
        const int grow = row0 + wm * 32 + mi * 16 + quad * 4;
        const int b = grow >> 2;
        float sn0 = 0.f, sn1 = 0.f, sn2 = 0.f, sn3 = 0.f;
        #pragma unroll
        for (int ni = 0; ni < 4; ni++) {
            int gc = col0 + wn * 64 + ni * 16 + l16;
            floatx4 a = acc[mi][ni];
            if (gc < EE) {
                float bias = bA[gc];
                float l0 = a[0] + bias, l1 = a[1] + bias, l2 = a[2] + bias, l3 = a[3] + bias;
                Lbar[b * EE + gc] = 0.25f * (l0 + l1 + l2 + l3);
                sn0 += logsigm(l0); sn1 += logsigm(l1); sn2 += logsigm(l2); sn3 += logsigm(l3);
            } else if (gc < CTOT) {
                int c2 = gc - EE;
                float bias = bF[c2];
                lgF[(b * 4 + 0) * 150 + c2] = a[0] + bias;
                lgF[(b * 4 + 1) * 150 + c2] = a[1] + bias;
                lgF[(b * 4 + 2) * 150 + c2] = a[2] + bias;
                lgF[(b * 4 + 3) * 150 + c2] = a[3] + bias;
            }
        }
        #pragma unroll
        for (int msk = 1; msk < 16; msk <<= 1) {
            sn0 += __shfl_xor(sn0, msk);
            sn1 += __shfl_xor(sn1, msk);
            sn2 += __shfl_xor(sn2, msk);
            sn3 += __shfl_xor(sn3, msk);
        }
        if (l16 == 0) {
            atomicAdd(&Sneg[b * 4 + 0], sn0);
            atomicAdd(&Sneg[b * 4 + 1], sn1);
            atomicAdd(&Sneg[b * 4 + 2], sn2);
            atomicAdd(&Sneg[b * 4 + 3], sn3);
        }
    }
}

// K4: per-graph finalization. grid 256, 256 threads (4 waves).
// Edges + KLD precomputed by kA; no A-scan here.
__global__ __launch_bounds__(256) void k4(const float* __restrict__ Fx,
                                          const float* __restrict__ coeff,
                                          const int* __restrict__ perms,
                                          const float* __restrict__ Lbar,
                                          const float* __restrict__ Sneg,
                                          const float* __restrict__ lgF,
                                          const int* __restrict__ edgesG,
                                          const int* __restrict__ cntG,
                                          const float* __restrict__ kldG,
                                          float* __restrict__ out) {
    const int b = blockIdx.x;
    const int t = threadIdx.x;
    const int w = t >> 6, lane = t & 63;
    __shared__ int   ip[PP * NN];
    __shared__ float Lb[EE];
    __shared__ int   edges[256];
    __shared__ float lgfs[600];
    __shared__ float mred[4], wmaxs[4];

    const int ne = cntG[b];
    for (int x = t; x < PP * NN; x += 256) {
        int p = x / NN, i = x - p * NN;
        ip[p * NN + perms[x]] = i;
    }
    for (int x = t; x < EE; x += 256) Lb[x] = Lbar[b * EE + x];
    for (int x = t; x < 600; x += 256) lgfs[x] = lgF[b * 600 + x];
    if (t < ne) edges[t] = edgesG[b * 256 + t];
    __syncthreads();

    // Fx terms: wave w handles sample m = w
    {
        float l0 = 0.f, l1 = 0.f, l2 = -INFINITY, x0 = 0.f, x1 = 0.f, x2 = 0.f;
        bool v = lane < NN;
        if (v) {
            l0 = lgfs[w * 150 + lane * 3 + 0];
            l1 = lgfs[w * 150 + lane * 3 + 1];
            l2 = lgfs[w * 150 + lane * 3 + 2];
            x0 = Fx[b * 150 + lane * 3 + 0];
            x1 = Fx[b * 150 + lane * 3 + 1];
            x2 = Fx[b * 150 + lane * 3 + 2];
        }
        float mx = wmax64(l2);
        float es = v ? expf(l2 - mx) : 0.f;
        es = wsum64(es);
        float lse = mx + logf(es);
        float val = 0.f;
        if (v) {
            val = coeff[0] * (logsigm(l0) + x0 * l0)
                + coeff[1] * (logsigm(l1) + x1 * l1)
                + coeff[2] * (x2 * (l2 - lse));
        }
        val = wsum64(val);
        if (lane == 0) mred[w] = val;
    }
    __syncthreads();

    float lmax = -INFINITY;
    for (int p = w; p < PP; p += 4) {
        const int* ipp = &ip[p * NN];
        float acc = 0.f;
        for (int x = lane; x < ne; x += 64) {
            int ed = edges[x];
            int iu = ipp[ed >> 8], iv = ipp[ed & 255];
            int ii = max(iu, iv), jj = min(iu, iv);
            acc += Lb[ii * (ii - 1) / 2 + jj];
        }
        acc = wsum64(acc);
        lmax = fmaxf(lmax, acc);
    }
    if (lane == 0) wmaxs[w] = lmax;
    __syncthreads();
    if (t == 0) {
        float dmax = fmaxf(fmaxf(wmaxs[0], wmaxs[1]), fmaxf(wmaxs[2], wmaxs[3]));
        float sbar = 0.25f * (Sneg[b * 4 + 0] + Sneg[b * 4 + 1] + Sneg[b * 4 + 2] + Sneg[b * 4 + 3]);
        float fxv  = 0.25f * (mred[0] + mred[1] + mred[2] + mred[3]);
        out[b] = (sbar + dmax) + fxv - kldG[b];
    }
}

extern "C" void kernel_launch(void* const* d_in, const int* in_sizes, int n_in,
                              void* d_out, int out_size, void* d_ws, size_t ws_size,
                              hipStream_t stream) {
    const float* mean   = (const float*)d_in[0];
    const float* logvar = (const float*)d_in[1];
    const float* eps    = (const float*)d_in[2];
    const float* W1     = (const float*)d_in[3];
    const float* b1     = (const float*)d_in[4];
    const float* WA     = (const float*)d_in[5];
    const float* bA     = (const float*)d_in[6];
    const float* WF     = (const float*)d_in[7];
    const float* bF     = (const float*)d_in[8];
    const float* A      = (const float*)d_in[9];
    const float* Fx     = (const float*)d_in[10];
    const float* coeff  = (const float*)d_in[11];
    const int*   perms  = (const int*)d_in[12];
    float* out = (float*)d_out;

    ushort* Wt   = (ushort*)d_ws;               // 1408*1024 bf16
    ushort* hB   = Wt + NPAD * 1024;            // 1024*1024 bf16
    float*  Lbar = (float*)(hB + 1024 * 1024);  // 256*1225
    float*  Sneg = Lbar + BB * EE;              // 1024 (zeroed by kA)
    float*  lgF  = Sneg + 1024;                 // 1024*150
    int*    edgesG = (int*)(lgF + 1024 * 150);  // 256*256
    int*    cntG   = edgesG + 256 * 256;        // 256
    float*  kldG   = (float*)(cntG + 256);      // 256

    kA<<<dim3(608), dim3(256), 0, stream>>>(mean, logvar, eps, W1, b1, WA, WF, A,
                                            hB, Wt, Sneg, edgesG, cntG, kldG);
    k2<<<dim3(11, 16), dim3(256), 0, stream>>>(hB, Wt, bA, bF, Lbar, Sneg, lgF);
    k4<<<dim3(BB), dim3(256), 0, stream>>>(Fx, coeff, perms, Lbar, Sneg, lgF,
                                           edgesG, cntG, kldG, out);
}